// Round 1
// baseline (1124.595 us; speedup 1.0000x reference)
//
#include <hip/hip_runtime.h>
#include <math.h>

// Problem constants (fixed by the reference):
//   N=50000 nodes, E=1600000 edges, F=64, H=128, ED=2, A=16
#define H_DIM 128

// ---------------------------------------------------------------------------
// K1: per-dst degree + edge_attr segment sum (for self-loop fill_value='mean')
__global__ void deg_kernel(const int* __restrict__ ei, const float* __restrict__ ea,
                           int* __restrict__ cnt, float* __restrict__ easum, int E) {
    int e = blockIdx.x * blockDim.x + threadIdx.x;
    if (e >= E) return;
    int d = ei[E + e];
    atomicAdd(&cnt[d], 1);
    atomicAdd(&easum[2 * d + 0], ea[2 * e + 0]);
    atomicAdd(&easum[2 * d + 1], ea[2 * e + 1]);
}

// ---------------------------------------------------------------------------
// K2: single-block exclusive scan of (deg+1) -> rowptr, pos; ea_mean in place
__global__ void scan_kernel(const int* __restrict__ cnt, float* __restrict__ ea_mean,
                            int* __restrict__ rowptr, int* __restrict__ pos,
                            int n, int total) {
    __shared__ int sums[1024];
    int t = threadIdx.x;
    int chunk = (n + 1023) / 1024;
    int lo = t * chunk, hi = min(lo + chunk, n);
    int s = 0;
    for (int i = lo; i < hi; ++i) s += cnt[i] + 1;
    sums[t] = s;
    __syncthreads();
    for (int off = 1; off < 1024; off <<= 1) {
        int tmp = (t >= off) ? sums[t - off] : 0;
        __syncthreads();
        sums[t] += tmp;
        __syncthreads();
    }
    int run = sums[t] - s;   // exclusive prefix
    for (int i = lo; i < hi; ++i) {
        rowptr[i] = run;
        pos[i] = run;
        run += cnt[i] + 1;
        float c = fmaxf((float)cnt[i], 1.0f);
        ea_mean[2 * i + 0] = ea_mean[2 * i + 0] / c;  // in place over easum
        ea_mean[2 * i + 1] = ea_mean[2 * i + 1] / c;
    }
    if (t == 0) rowptr[n] = total;
}

// ---------------------------------------------------------------------------
// K3: scatter edges (originals + self loops) into dst-grouped CSR slots
__global__ void scatter_kernel(const int* __restrict__ ei, const float* __restrict__ ea,
                               const float* __restrict__ ea_mean, int* __restrict__ pos,
                               int* __restrict__ csr_src, float2* __restrict__ csr_ea,
                               int E, int n) {
    int e = blockIdx.x * blockDim.x + threadIdx.x;
    if (e >= E + n) return;
    int s, d; float2 v;
    if (e < E) {
        s = ei[e]; d = ei[E + e];
        v = make_float2(ea[2 * e], ea[2 * e + 1]);
    } else {
        s = d = e - E;
        v = make_float2(ea_mean[2 * d], ea_mean[2 * d + 1]);
    }
    int k = atomicAdd(&pos[d], 1);
    csr_src[k] = s;
    csr_ea[k] = v;
}

// ---------------------------------------------------------------------------
// K4: c = We^T @ a_edge for both layers (2 floats each). One wave.
__global__ void cvec_kernel(const float* __restrict__ We1, const float* __restrict__ ae1,
                            const float* __restrict__ We2, const float* __restrict__ ae2,
                            float* __restrict__ c) {
    int t = threadIdx.x;  // 64 threads
    float a1x = ae1[t], a1y = ae1[t + 64];
    float a2x = ae2[t], a2y = ae2[t + 64];
    float v0 = We1[t] * a1x + We1[t + 64] * a1y;
    float v1 = We1[128 + t] * a1x + We1[192 + t] * a1y;
    float v2 = We2[t] * a2x + We2[t + 64] * a2y;
    float v3 = We2[128 + t] * a2x + We2[192 + t] * a2y;
    for (int off = 32; off; off >>= 1) {
        v0 += __shfl_xor(v0, off);
        v1 += __shfl_xor(v1, off);
        v2 += __shfl_xor(v2, off);
        v3 += __shfl_xor(v3, off);
    }
    if (t == 0) { c[0] = v0; c[1] = v1; c[2] = v2; c[3] = v3; }
}

// ---------------------------------------------------------------------------
// K5: h = X @ W  (X: n x FIN, W: FIN x 128). 32 rows/block, 4x4 per thread.
template <int FIN>
__global__ __launch_bounds__(256) void gemm_kernel(const float* __restrict__ X,
                                                   const float* __restrict__ W,
                                                   float* __restrict__ Hout, int n) {
    __shared__ float xs[32 * FIN];
    int tid = threadIdx.x;
    int r0 = blockIdx.x * 32;
    for (int idx = tid; idx < 32 * FIN; idx += 256) {
        int r = idx / FIN, k = idx - r * FIN;
        int row = r0 + r;
        xs[idx] = (row < n) ? X[row * FIN + k] : 0.0f;
    }
    __syncthreads();
    int tcol = tid & 31;   // cols 4*tcol .. +3
    int trow = tid >> 5;   // rows 4*trow .. +3
    float acc[4][4] = {{0.f}};
    const float* wp = W + tcol * 4;
    const float* x0p = &xs[(trow * 4 + 0) * FIN];
    const float* x1p = &xs[(trow * 4 + 1) * FIN];
    const float* x2p = &xs[(trow * 4 + 2) * FIN];
    const float* x3p = &xs[(trow * 4 + 3) * FIN];
#pragma unroll 8
    for (int k = 0; k < FIN; ++k) {
        float4 w4 = *(const float4*)(wp + k * H_DIM);
        float x0 = x0p[k], x1 = x1p[k], x2 = x2p[k], x3 = x3p[k];
        acc[0][0] += x0 * w4.x; acc[0][1] += x0 * w4.y; acc[0][2] += x0 * w4.z; acc[0][3] += x0 * w4.w;
        acc[1][0] += x1 * w4.x; acc[1][1] += x1 * w4.y; acc[1][2] += x1 * w4.z; acc[1][3] += x1 * w4.w;
        acc[2][0] += x2 * w4.x; acc[2][1] += x2 * w4.y; acc[2][2] += x2 * w4.z; acc[2][3] += x2 * w4.w;
        acc[3][0] += x3 * w4.x; acc[3][1] += x3 * w4.y; acc[3][2] += x3 * w4.z; acc[3][3] += x3 * w4.w;
    }
#pragma unroll
    for (int r = 0; r < 4; ++r) {
        int row = r0 + trow * 4 + r;
        if (row < n) {
            float4 o = make_float4(acc[r][0], acc[r][1], acc[r][2], acc[r][3]);
            *(float4*)&Hout[row * H_DIM + tcol * 4] = o;
        }
    }
}

// ---------------------------------------------------------------------------
// K6: hs[i] = h[i]·a_s, hd[i] = h[i]·a_d.  One wave per node.
__global__ void hshd_kernel(const float* __restrict__ h, const float* __restrict__ a_s,
                            const float* __restrict__ a_d, float* __restrict__ hs,
                            float* __restrict__ hd, int n) {
    int w = (blockIdx.x * blockDim.x + threadIdx.x) >> 6;
    int lane = threadIdx.x & 63;
    if (w >= n) return;
    float2 hv = *(const float2*)&h[w * H_DIM + lane * 2];
    float2 s2 = *(const float2*)&a_s[lane * 2];
    float2 d2 = *(const float2*)&a_d[lane * 2];
    float ss = hv.x * s2.x + hv.y * s2.y;
    float sd = hv.x * d2.x + hv.y * d2.y;
    for (int off = 32; off; off >>= 1) {
        ss += __shfl_xor(ss, off);
        sd += __shfl_xor(sd, off);
    }
    if (lane == 0) { hs[w] = ss; hd[w] = sd; }
}

// ---------------------------------------------------------------------------
// K7: per-node attention logits (leaky_relu) + running max. One wave per node.
__global__ void agg1_kernel(const int* __restrict__ rowptr, const int* __restrict__ csr_src,
                            const float2* __restrict__ csr_ea, const float* __restrict__ hs,
                            const float* __restrict__ hd, const float* __restrict__ cvec,
                            int coff, float* __restrict__ alpha, float* __restrict__ mbuf,
                            int n) {
    int w = (blockIdx.x * blockDim.x + threadIdx.x) >> 6;
    int lane = threadIdx.x & 63;
    if (w >= n) return;
    int beg = rowptr[w], end = rowptr[w + 1];
    float hdv = hd[w];
    float c0 = cvec[coff], c1 = cvec[coff + 1];
    float mymax = -1e30f;
    for (int k = beg + lane; k < end; k += 64) {
        float2 eav = csr_ea[k];
        float l = hs[csr_src[k]] + hdv + c0 * eav.x + c1 * eav.y;
        l = (l >= 0.f) ? l : 0.2f * l;
        alpha[k] = l;  // store raw logit
        mymax = fmaxf(mymax, l);
    }
    for (int off = 32; off; off >>= 1) mymax = fmaxf(mymax, __shfl_xor(mymax, off));
    if (lane == 0) mbuf[w] = mymax;
}

// ---------------------------------------------------------------------------
// K8: softmax denom + weighted gather-sum of h[src] + bias + relu.
// One wave per node; phase C re-derives p=exp(l-m) wave-uniformly (logits were
// written in K7, so visible across the kernel boundary -> no intra-wave
// global write->read hazard).
__global__ void agg2_kernel(const int* __restrict__ rowptr, const int* __restrict__ csr_src,
                            const float* __restrict__ alpha, const float* __restrict__ mbuf,
                            const float* __restrict__ hmat, const float* __restrict__ bias,
                            float* __restrict__ out, int n) {
    int w = (blockIdx.x * blockDim.x + threadIdx.x) >> 6;
    int lane = threadIdx.x & 63;
    if (w >= n) return;
    int beg = rowptr[w], end = rowptr[w + 1];
    float m = mbuf[w];
    float mysum = 0.f;
    for (int k = beg + lane; k < end; k += 64) mysum += __expf(alpha[k] - m);
    for (int off = 32; off; off >>= 1) mysum += __shfl_xor(mysum, off);
    float scale = 1.f / (mysum + 1e-16f);
    float2 acc = make_float2(0.f, 0.f);
    for (int k = beg; k < end; ++k) {       // k is wave-uniform
        int s = csr_src[k];
        float a = __expf(alpha[k] - m) * scale;
        float2 hv = *(const float2*)&hmat[s * H_DIM + lane * 2];
        acc.x += a * hv.x;
        acc.y += a * hv.y;
    }
    float2 b2 = *(const float2*)&bias[lane * 2];
    float ox = fmaxf(acc.x + b2.x, 0.f);
    float oy = fmaxf(acc.y + b2.y, 0.f);
    *(float2*)&out[w * H_DIM + lane * 2] = make_float2(ox, oy);
}

// ---------------------------------------------------------------------------
// K9: column sums of h (for mean pooling)
__global__ void pool_kernel(const float* __restrict__ hmat, float* __restrict__ pooled,
                            int n) {
    __shared__ float red[256];
    int col = threadIdx.x & 127;
    int half = threadIdx.x >> 7;
    int rows_per_block = (n + gridDim.x - 1) / gridDim.x;
    int r0 = blockIdx.x * rows_per_block;
    int r1 = min(r0 + rows_per_block, n);
    float s = 0.f;
    for (int r = r0 + half; r < r1; r += 2) s += hmat[r * H_DIM + col];
    red[threadIdx.x] = s;
    __syncthreads();
    if (half == 0) atomicAdd(&pooled[col], red[threadIdx.x] + red[threadIdx.x + 128]);
}

// ---------------------------------------------------------------------------
// K10: out = tanh(mean(h) @ Wfc + bfc)   (tiny)
__global__ void final_kernel(const float* __restrict__ pooled, const float* __restrict__ Wfc,
                             const float* __restrict__ bfc, float* __restrict__ out, int n) {
    int t = threadIdx.x;
    if (t >= 16) return;
    float inv_n = 1.0f / (float)n;
    float s = 0.f;
    for (int j = 0; j < 128; ++j) s += pooled[j] * inv_n * Wfc[j * 16 + t];
    out[t] = tanhf(s + bfc[t]);
}

// ---------------------------------------------------------------------------
extern "C" void kernel_launch(void* const* d_in, const int* in_sizes, int n_in,
                              void* d_out, int out_size, void* d_ws, size_t ws_size,
                              hipStream_t stream) {
    const float* x   = (const float*)d_in[0];
    const int*   ei  = (const int*)d_in[1];
    const float* ea  = (const float*)d_in[2];
    const float* W1  = (const float*)d_in[3];
    const float* We1 = (const float*)d_in[4];
    const float* as1 = (const float*)d_in[5];
    const float* ad1 = (const float*)d_in[6];
    const float* ae1 = (const float*)d_in[7];
    const float* b1  = (const float*)d_in[8];
    const float* W2  = (const float*)d_in[9];
    const float* We2 = (const float*)d_in[10];
    const float* as2 = (const float*)d_in[11];
    const float* ad2 = (const float*)d_in[12];
    const float* ae2 = (const float*)d_in[13];
    const float* b2  = (const float*)d_in[14];
    const float* Wfc = (const float*)d_in[15];
    const float* bfc = (const float*)d_in[16];
    float* out = (float*)d_out;

    const int n = in_sizes[0] / 64;      // 50000
    const int E = in_sizes[1] / 2;       // 1600000
    const int E2 = E + n;

    // workspace layout (floats, 256B-aligned blocks)
    size_t o = 0;
    auto alloc = [&](size_t count) { size_t r = o; o += (count + 63) & ~(size_t)63; return r; };
    size_t o_cnt    = alloc(n);            // int
    size_t o_easum  = alloc(2 * (size_t)n);
    size_t o_rowptr = alloc(n + 1);        // int
    size_t o_pos    = alloc(n);            // int
    size_t o_csrsrc = alloc(E2);           // int
    size_t o_csrea  = alloc(2 * (size_t)E2);
    size_t o_alpha  = alloc(E2);
    size_t o_m      = alloc(n);
    size_t o_hs     = alloc(n);
    size_t o_hd     = alloc(n);
    size_t o_bufA   = alloc((size_t)n * H_DIM);
    size_t o_bufB   = alloc((size_t)n * H_DIM);
    size_t o_c      = alloc(4);
    size_t o_pool   = alloc(128);
    (void)ws_size;  // ~80 MB needed

    float* wsf = (float*)d_ws;
    hipMemsetAsync(wsf + o_cnt, 0, n * sizeof(int), stream);
    hipMemsetAsync(wsf + o_easum, 0, 2 * (size_t)n * sizeof(float), stream);
    hipMemsetAsync(wsf + o_pool, 0, 128 * sizeof(float), stream);

    deg_kernel<<<(E + 255) / 256, 256, 0, stream>>>(ei, ea, (int*)(wsf + o_cnt),
                                                    wsf + o_easum, E);
    scan_kernel<<<1, 1024, 0, stream>>>((int*)(wsf + o_cnt), wsf + o_easum,
                                        (int*)(wsf + o_rowptr), (int*)(wsf + o_pos), n, E2);
    scatter_kernel<<<(E2 + 255) / 256, 256, 0, stream>>>(ei, ea, wsf + o_easum,
        (int*)(wsf + o_pos), (int*)(wsf + o_csrsrc), (float2*)(wsf + o_csrea), E, n);
    cvec_kernel<<<1, 64, 0, stream>>>(We1, ae1, We2, ae2, wsf + o_c);

    int wgrid = (n + 3) / 4;  // 4 waves (nodes) per 256-thread block

    // ---- layer 1 (F=64 -> H=128) ----
    gemm_kernel<64><<<(n + 31) / 32, 256, 0, stream>>>(x, W1, wsf + o_bufB, n);
    hshd_kernel<<<wgrid, 256, 0, stream>>>(wsf + o_bufB, as1, ad1, wsf + o_hs, wsf + o_hd, n);
    agg1_kernel<<<wgrid, 256, 0, stream>>>((int*)(wsf + o_rowptr), (int*)(wsf + o_csrsrc),
        (const float2*)(wsf + o_csrea), wsf + o_hs, wsf + o_hd, wsf + o_c, 0,
        wsf + o_alpha, wsf + o_m, n);
    agg2_kernel<<<wgrid, 256, 0, stream>>>((int*)(wsf + o_rowptr), (int*)(wsf + o_csrsrc),
        wsf + o_alpha, wsf + o_m, wsf + o_bufB, b1, wsf + o_bufA, n);

    // ---- layer 2 (H=128 -> H=128) ----
    gemm_kernel<128><<<(n + 31) / 32, 256, 0, stream>>>(wsf + o_bufA, W2, wsf + o_bufB, n);
    hshd_kernel<<<wgrid, 256, 0, stream>>>(wsf + o_bufB, as2, ad2, wsf + o_hs, wsf + o_hd, n);
    agg1_kernel<<<wgrid, 256, 0, stream>>>((int*)(wsf + o_rowptr), (int*)(wsf + o_csrsrc),
        (const float2*)(wsf + o_csrea), wsf + o_hs, wsf + o_hd, wsf + o_c, 2,
        wsf + o_alpha, wsf + o_m, n);
    agg2_kernel<<<wgrid, 256, 0, stream>>>((int*)(wsf + o_rowptr), (int*)(wsf + o_csrsrc),
        wsf + o_alpha, wsf + o_m, wsf + o_bufB, b2, wsf + o_bufA, n);

    // ---- pooling + head ----
    pool_kernel<<<256, 256, 0, stream>>>(wsf + o_bufA, wsf + o_pool, n);
    final_kernel<<<1, 64, 0, stream>>>(wsf + o_pool, Wfc, bfc, out, n);
}

// Round 2
// 725.651 us; speedup vs baseline: 1.5498x; 1.5498x over previous
//
#include <hip/hip_runtime.h>
#include <math.h>

// Problem constants (fixed by the reference):
//   N=50000 nodes, E=1600000 edges, F=64, H=128, ED=2, A=16
#define H_DIM 128

// ---------------------------------------------------------------------------
// K1: per-dst degree (self-loop ea-mean handled analytically in agg_kernel)
__global__ void deg_kernel(const int* __restrict__ ei, int* __restrict__ cnt, int E) {
    int e = blockIdx.x * blockDim.x + threadIdx.x;
    if (e >= E) return;
    atomicAdd(&cnt[ei[E + e]], 1);
}

// ---------------------------------------------------------------------------
// K2: single-block exclusive scan of deg -> rowptr, pos
__global__ void scan_kernel(const int* __restrict__ cnt, int* __restrict__ rowptr,
                            int* __restrict__ pos, int n, int total) {
    __shared__ int sums[1024];
    int t = threadIdx.x;
    int chunk = (n + 1023) / 1024;
    int lo = t * chunk, hi = min(lo + chunk, n);
    int s = 0;
    for (int i = lo; i < hi; ++i) s += cnt[i];
    sums[t] = s;
    __syncthreads();
    for (int off = 1; off < 1024; off <<= 1) {
        int tmp = (t >= off) ? sums[t - off] : 0;
        __syncthreads();
        sums[t] += tmp;
        __syncthreads();
    }
    int run = sums[t] - s;   // exclusive prefix
    for (int i = lo; i < hi; ++i) {
        rowptr[i] = run;
        pos[i] = run;
        run += cnt[i];
    }
    if (t == 0) rowptr[n] = total;
}

// ---------------------------------------------------------------------------
// K3: c = We^T @ a_edge for both layers (2 floats each). One wave.
__global__ void cvec_kernel(const float* __restrict__ We1, const float* __restrict__ ae1,
                            const float* __restrict__ We2, const float* __restrict__ ae2,
                            float* __restrict__ c) {
    int t = threadIdx.x;  // 64 threads
    float a1x = ae1[t], a1y = ae1[t + 64];
    float a2x = ae2[t], a2y = ae2[t + 64];
    float v0 = We1[t] * a1x + We1[t + 64] * a1y;
    float v1 = We1[128 + t] * a1x + We1[192 + t] * a1y;
    float v2 = We2[t] * a2x + We2[t + 64] * a2y;
    float v3 = We2[128 + t] * a2x + We2[192 + t] * a2y;
    for (int off = 32; off; off >>= 1) {
        v0 += __shfl_xor(v0, off);
        v1 += __shfl_xor(v1, off);
        v2 += __shfl_xor(v2, off);
        v3 += __shfl_xor(v3, off);
    }
    if (t == 0) { c[0] = v0; c[1] = v1; c[2] = v2; c[3] = v3; }
}

// ---------------------------------------------------------------------------
// K4: scatter edges into dst-grouped CSR; entry = (src, edot_layer1, edot_layer2, 0)
__global__ void scatter_kernel(const int* __restrict__ ei, const float* __restrict__ ea,
                               const float* __restrict__ cvec, int* __restrict__ pos,
                               int4* __restrict__ csr, int E) {
    int e = blockIdx.x * blockDim.x + threadIdx.x;
    if (e >= E) return;
    int s = ei[e], d = ei[E + e];
    float2 v = ((const float2*)ea)[e];
    float d1 = cvec[0] * v.x + cvec[1] * v.y;
    float d2 = cvec[2] * v.x + cvec[3] * v.y;
    int k = atomicAdd(&pos[d], 1);
    csr[k] = make_int4(s, __float_as_int(d1), __float_as_int(d2), 0);
}

// ---------------------------------------------------------------------------
// K5: h = X @ W  (X: n x FIN, W: FIN x 128). 32 rows/block, 4x4 per thread.
template <int FIN>
__global__ __launch_bounds__(256) void gemm_kernel(const float* __restrict__ X,
                                                   const float* __restrict__ W,
                                                   float* __restrict__ Hout, int n) {
    __shared__ float xs[32 * FIN];
    int tid = threadIdx.x;
    int r0 = blockIdx.x * 32;
    for (int idx = tid; idx < 32 * FIN; idx += 256) {
        int r = idx / FIN, k = idx - r * FIN;
        int row = r0 + r;
        xs[idx] = (row < n) ? X[row * FIN + k] : 0.0f;
    }
    __syncthreads();
    int tcol = tid & 31;   // cols 4*tcol .. +3
    int trow = tid >> 5;   // rows 4*trow .. +3
    float acc[4][4] = {{0.f}};
    const float* wp = W + tcol * 4;
    const float* x0p = &xs[(trow * 4 + 0) * FIN];
    const float* x1p = &xs[(trow * 4 + 1) * FIN];
    const float* x2p = &xs[(trow * 4 + 2) * FIN];
    const float* x3p = &xs[(trow * 4 + 3) * FIN];
#pragma unroll 8
    for (int k = 0; k < FIN; ++k) {
        float4 w4 = *(const float4*)(wp + k * H_DIM);
        float x0 = x0p[k], x1 = x1p[k], x2 = x2p[k], x3 = x3p[k];
        acc[0][0] += x0 * w4.x; acc[0][1] += x0 * w4.y; acc[0][2] += x0 * w4.z; acc[0][3] += x0 * w4.w;
        acc[1][0] += x1 * w4.x; acc[1][1] += x1 * w4.y; acc[1][2] += x1 * w4.z; acc[1][3] += x1 * w4.w;
        acc[2][0] += x2 * w4.x; acc[2][1] += x2 * w4.y; acc[2][2] += x2 * w4.z; acc[2][3] += x2 * w4.w;
        acc[3][0] += x3 * w4.x; acc[3][1] += x3 * w4.y; acc[3][2] += x3 * w4.z; acc[3][3] += x3 * w4.w;
    }
#pragma unroll
    for (int r = 0; r < 4; ++r) {
        int row = r0 + trow * 4 + r;
        if (row < n) {
            float4 o = make_float4(acc[r][0], acc[r][1], acc[r][2], acc[r][3]);
            *(float4*)&Hout[row * H_DIM + tcol * 4] = o;
        }
    }
}

// ---------------------------------------------------------------------------
// K6: hs[i] = h[i]·a_s, hd[i] = h[i]·a_d.  One wave per node.
__global__ void hshd_kernel(const float* __restrict__ h, const float* __restrict__ a_s,
                            const float* __restrict__ a_d, float* __restrict__ hs,
                            float* __restrict__ hd, int n) {
    int w = (blockIdx.x * blockDim.x + threadIdx.x) >> 6;
    int lane = threadIdx.x & 63;
    if (w >= n) return;
    float2 hv = *(const float2*)&h[w * H_DIM + lane * 2];
    float2 s2 = *(const float2*)&a_s[lane * 2];
    float2 d2 = *(const float2*)&a_d[lane * 2];
    float ss = hv.x * s2.x + hv.y * s2.y;
    float sd = hv.x * d2.x + hv.y * d2.y;
    for (int off = 32; off; off >>= 1) {
        ss += __shfl_xor(ss, off);
        sd += __shfl_xor(sd, off);
    }
    if (lane == 0) { hs[w] = ss; hd[w] = sd; }
}

// ---------------------------------------------------------------------------
// K7: fused GAT aggregation: logits + softmax + weighted gather + bias + relu.
// One wave per node. Self-loop (fill_value='mean') handled analytically:
// its edge-dot is the row-mean of the stored per-edge dots.
__global__ __launch_bounds__(256) void agg_kernel(
        const int* __restrict__ rowptr, const int4* __restrict__ csr,
        const float* __restrict__ hs, const float* __restrict__ hd,
        const float* __restrict__ hmat, const float* __restrict__ bias,
        int dsel, float* __restrict__ out, int n) {
    int w = (blockIdx.x * blockDim.x + threadIdx.x) >> 6;
    int lane = threadIdx.x & 63;
    if (w >= n) return;
    int beg = rowptr[w], end = rowptr[w + 1];
    int len = end - beg;
    float hdv = hd[w];
    float hsw = hs[w];
    int half = lane >> 5;    // which 32-lane group
    int col = lane & 31;     // float4 index within the 128-wide row
    float4 acc = make_float4(0.f, 0.f, 0.f, 0.f);
    float m, scale, lself;

    if (len <= 64) {
        // ---- fast path: whole row resident in one wave-load ----
        bool valid = lane < len;
        int4 c4 = valid ? csr[beg + lane] : make_int4(0, 0, 0, 0);
        float ed = valid ? __int_as_float(dsel ? c4.z : c4.y) : 0.f;
        float l = hs[c4.x] + hdv + ed;
        l = (l >= 0.f) ? l : 0.2f * l;
        float mymax = valid ? l : -1e30f;
        float edsum = ed;
        for (int off = 32; off; off >>= 1) {
            mymax = fmaxf(mymax, __shfl_xor(mymax, off));
            edsum += __shfl_xor(edsum, off);
        }
        lself = hsw + hdv + edsum / fmaxf((float)len, 1.0f);
        lself = (lself >= 0.f) ? lself : 0.2f * lself;
        m = fmaxf(mymax, lself);
        float p = valid ? __expf(l - m) : 0.f;
        float psum = p;
        for (int off = 32; off; off >>= 1) psum += __shfl_xor(psum, off);
        psum += __expf(lself - m);
        scale = 1.f / (psum + 1e-16f);
        float pn = p * scale;
        int src = c4.x;
        // gather: two edges in flight (half-wave float4 groups)
        for (int j = half; j < len; j += 2) {
            float a = __shfl(pn, j);
            int sj = __shfl(src, j);
            const float4 hv = *(const float4*)&hmat[(size_t)sj * H_DIM + col * 4];
            acc.x += a * hv.x; acc.y += a * hv.y; acc.z += a * hv.z; acc.w += a * hv.w;
        }
    } else {
        // ---- generic path (rare): 3-pass over chunks of 64 ----
        float mymax = -1e30f, edsum = 0.f;
        for (int base = beg; base < end; base += 64) {
            int k = base + lane;
            if (k < end) {
                int4 c4 = csr[k];
                float ed = __int_as_float(dsel ? c4.z : c4.y);
                edsum += ed;
                float l = hs[c4.x] + hdv + ed;
                l = (l >= 0.f) ? l : 0.2f * l;
                mymax = fmaxf(mymax, l);
            }
        }
        for (int off = 32; off; off >>= 1) {
            mymax = fmaxf(mymax, __shfl_xor(mymax, off));
            edsum += __shfl_xor(edsum, off);
        }
        lself = hsw + hdv + edsum / fmaxf((float)len, 1.0f);
        lself = (lself >= 0.f) ? lself : 0.2f * lself;
        m = fmaxf(mymax, lself);
        float psum = 0.f;
        for (int base = beg; base < end; base += 64) {
            int k = base + lane;
            if (k < end) {
                int4 c4 = csr[k];
                float ed = __int_as_float(dsel ? c4.z : c4.y);
                float l = hs[c4.x] + hdv + ed;
                l = (l >= 0.f) ? l : 0.2f * l;
                psum += __expf(l - m);
            }
        }
        for (int off = 32; off; off >>= 1) psum += __shfl_xor(psum, off);
        psum += __expf(lself - m);
        scale = 1.f / (psum + 1e-16f);
        for (int base = beg; base < end; base += 64) {
            int k = base + lane;
            float pn = 0.f; int src = 0;
            if (k < end) {
                int4 c4 = csr[k];
                float ed = __int_as_float(dsel ? c4.z : c4.y);
                float l = hs[c4.x] + hdv + ed;
                l = (l >= 0.f) ? l : 0.2f * l;
                pn = __expf(l - m) * scale;
                src = c4.x;
            }
            int cl = min(end - base, 64);
            for (int j = half; j < cl; j += 2) {
                float a = __shfl(pn, j);
                int sj = __shfl(src, j);
                const float4 hv = *(const float4*)&hmat[(size_t)sj * H_DIM + col * 4];
                acc.x += a * hv.x; acc.y += a * hv.y; acc.z += a * hv.z; acc.w += a * hv.w;
            }
        }
    }

    // self-loop contribution (half 0 only)
    if (half == 0) {
        float a = __expf(lself - m) * scale;
        const float4 hv = *(const float4*)&hmat[(size_t)w * H_DIM + col * 4];
        acc.x += a * hv.x; acc.y += a * hv.y; acc.z += a * hv.z; acc.w += a * hv.w;
    }
    // combine the two half-wave partial sums: lanes 0-31 pull from lane col+32
    float4 oth;
    oth.x = __shfl(acc.x, col + 32);
    oth.y = __shfl(acc.y, col + 32);
    oth.z = __shfl(acc.z, col + 32);
    oth.w = __shfl(acc.w, col + 32);
    if (half == 0) {
        float4 b4 = *(const float4*)&bias[col * 4];
        float4 o;
        o.x = fmaxf(acc.x + oth.x + b4.x, 0.f);
        o.y = fmaxf(acc.y + oth.y + b4.y, 0.f);
        o.z = fmaxf(acc.z + oth.z + b4.z, 0.f);
        o.w = fmaxf(acc.w + oth.w + b4.w, 0.f);
        *(float4*)&out[(size_t)w * H_DIM + col * 4] = o;
    }
}

// ---------------------------------------------------------------------------
// K8: column sums of h (for mean pooling)
__global__ void pool_kernel(const float* __restrict__ hmat, float* __restrict__ pooled,
                            int n) {
    __shared__ float red[256];
    int col = threadIdx.x & 127;
    int half = threadIdx.x >> 7;
    int rows_per_block = (n + gridDim.x - 1) / gridDim.x;
    int r0 = blockIdx.x * rows_per_block;
    int r1 = min(r0 + rows_per_block, n);
    float s = 0.f;
    for (int r = r0 + half; r < r1; r += 2) s += hmat[r * H_DIM + col];
    red[threadIdx.x] = s;
    __syncthreads();
    if (half == 0) atomicAdd(&pooled[col], red[threadIdx.x] + red[threadIdx.x + 128]);
}

// ---------------------------------------------------------------------------
// K9: out = tanh(mean(h) @ Wfc + bfc)   (tiny)
__global__ void final_kernel(const float* __restrict__ pooled, const float* __restrict__ Wfc,
                             const float* __restrict__ bfc, float* __restrict__ out, int n) {
    int t = threadIdx.x;
    if (t >= 16) return;
    float inv_n = 1.0f / (float)n;
    float s = 0.f;
    for (int j = 0; j < 128; ++j) s += pooled[j] * inv_n * Wfc[j * 16 + t];
    out[t] = tanhf(s + bfc[t]);
}

// ---------------------------------------------------------------------------
extern "C" void kernel_launch(void* const* d_in, const int* in_sizes, int n_in,
                              void* d_out, int out_size, void* d_ws, size_t ws_size,
                              hipStream_t stream) {
    const float* x   = (const float*)d_in[0];
    const int*   ei  = (const int*)d_in[1];
    const float* ea  = (const float*)d_in[2];
    const float* W1  = (const float*)d_in[3];
    const float* We1 = (const float*)d_in[4];
    const float* as1 = (const float*)d_in[5];
    const float* ad1 = (const float*)d_in[6];
    const float* ae1 = (const float*)d_in[7];
    const float* b1  = (const float*)d_in[8];
    const float* W2  = (const float*)d_in[9];
    const float* We2 = (const float*)d_in[10];
    const float* as2 = (const float*)d_in[11];
    const float* ad2 = (const float*)d_in[12];
    const float* ae2 = (const float*)d_in[13];
    const float* b2  = (const float*)d_in[14];
    const float* Wfc = (const float*)d_in[15];
    const float* bfc = (const float*)d_in[16];
    float* out = (float*)d_out;

    const int n = in_sizes[0] / 64;      // 50000
    const int E = in_sizes[1] / 2;       // 1600000

    // workspace layout (floats, 256B-aligned blocks)
    size_t o = 0;
    auto alloc = [&](size_t count) { size_t r = o; o += (count + 63) & ~(size_t)63; return r; };
    size_t o_cnt    = alloc(n);                  // int
    size_t o_rowptr = alloc(n + 1);              // int
    size_t o_pos    = alloc(n);                  // int
    size_t o_csr    = alloc(4 * (size_t)E);      // int4 per edge
    size_t o_hs     = alloc(n);
    size_t o_hd     = alloc(n);
    size_t o_bufA   = alloc((size_t)n * H_DIM);
    size_t o_bufB   = alloc((size_t)n * H_DIM);
    size_t o_c      = alloc(4);
    size_t o_pool   = alloc(128);
    (void)ws_size;  // ~78 MB needed

    float* wsf = (float*)d_ws;
    hipMemsetAsync(wsf + o_cnt, 0, n * sizeof(int), stream);
    hipMemsetAsync(wsf + o_pool, 0, 128 * sizeof(float), stream);

    deg_kernel<<<(E + 255) / 256, 256, 0, stream>>>(ei, (int*)(wsf + o_cnt), E);
    scan_kernel<<<1, 1024, 0, stream>>>((int*)(wsf + o_cnt), (int*)(wsf + o_rowptr),
                                        (int*)(wsf + o_pos), n, E);
    cvec_kernel<<<1, 64, 0, stream>>>(We1, ae1, We2, ae2, wsf + o_c);
    scatter_kernel<<<(E + 255) / 256, 256, 0, stream>>>(ei, ea, wsf + o_c,
        (int*)(wsf + o_pos), (int4*)(wsf + o_csr), E);

    int wgrid = (n + 3) / 4;  // 4 waves (nodes) per 256-thread block

    // ---- layer 1 (F=64 -> H=128) ----
    gemm_kernel<64><<<(n + 31) / 32, 256, 0, stream>>>(x, W1, wsf + o_bufB, n);
    hshd_kernel<<<wgrid, 256, 0, stream>>>(wsf + o_bufB, as1, ad1, wsf + o_hs, wsf + o_hd, n);
    agg_kernel<<<wgrid, 256, 0, stream>>>((int*)(wsf + o_rowptr), (const int4*)(wsf + o_csr),
        wsf + o_hs, wsf + o_hd, wsf + o_bufB, b1, 0, wsf + o_bufA, n);

    // ---- layer 2 (H=128 -> H=128) ----
    gemm_kernel<128><<<(n + 31) / 32, 256, 0, stream>>>(wsf + o_bufA, W2, wsf + o_bufB, n);
    hshd_kernel<<<wgrid, 256, 0, stream>>>(wsf + o_bufB, as2, ad2, wsf + o_hs, wsf + o_hd, n);
    agg_kernel<<<wgrid, 256, 0, stream>>>((int*)(wsf + o_rowptr), (const int4*)(wsf + o_csr),
        wsf + o_hs, wsf + o_hd, wsf + o_bufB, b2, 1, wsf + o_bufA, n);

    // ---- pooling + head ----
    pool_kernel<<<256, 256, 0, stream>>>(wsf + o_bufA, wsf + o_pool, n);
    final_kernel<<<1, 64, 0, stream>>>(wsf + o_pool, Wfc, bfc, out, n);
}

// Round 3
// 654.170 us; speedup vs baseline: 1.7191x; 1.1093x over previous
//
#include <hip/hip_runtime.h>
#include <math.h>

// Problem constants: N=50000, E=1600000, F=64, H=128, ED=2, A=16
#define H_DIM 128
#define CPAD 4   // cursor padding (ints) to spread atomics across cache lines

typedef int v4i __attribute__((ext_vector_type(4)));

// ---------------------------------------------------------------------------
// K0: all tiny precomputes in one block.
//   c[0..3]  = We^T @ a_edge (both layers)
//   vs1/vd1  = W1 @ a_s1 / W1 @ a_d1   (64 each)
//   vs2/vd2  = W2 @ a_s2 / W2 @ a_d2   (128 each)
__global__ void prep_kernel(const float* __restrict__ We1, const float* __restrict__ ae1,
                            const float* __restrict__ We2, const float* __restrict__ ae2,
                            const float* __restrict__ W1, const float* __restrict__ as1,
                            const float* __restrict__ ad1,
                            const float* __restrict__ W2, const float* __restrict__ as2,
                            const float* __restrict__ ad2,
                            float* __restrict__ c, float* __restrict__ vs1,
                            float* __restrict__ vd1, float* __restrict__ vs2,
                            float* __restrict__ vd2) {
    int t = threadIdx.x;  // 256 threads
    if (t < 64) {
        float s = 0.f, d = 0.f;
        for (int h = 0; h < 128; ++h) {
            float w = W1[t * 128 + h];
            s += w * as1[h];
            d += w * ad1[h];
        }
        vs1[t] = s; vd1[t] = d;
    } else if (t < 192) {
        int k = t - 64;
        float s = 0.f, d = 0.f;
        for (int h = 0; h < 128; ++h) {
            float w = W2[k * 128 + h];
            s += w * as2[h];
            d += w * ad2[h];
        }
        vs2[k] = s; vd2[k] = d;
    } else {
        int l = t - 192;  // lane of wave 3
        float a1x = ae1[l], a1y = ae1[l + 64];
        float a2x = ae2[l], a2y = ae2[l + 64];
        float v0 = We1[l] * a1x + We1[l + 64] * a1y;
        float v1 = We1[128 + l] * a1x + We1[192 + l] * a1y;
        float v2 = We2[l] * a2x + We2[l + 64] * a2y;
        float v3 = We2[128 + l] * a2x + We2[192 + l] * a2y;
        for (int off = 32; off; off >>= 1) {
            v0 += __shfl_xor(v0, off);
            v1 += __shfl_xor(v1, off);
            v2 += __shfl_xor(v2, off);
            v3 += __shfl_xor(v3, off);
        }
        if (l == 0) { c[0] = v0; c[1] = v1; c[2] = v2; c[3] = v3; }
    }
}

// ---------------------------------------------------------------------------
// K1: per-dst degree (padded counters)
__global__ void deg_kernel(const int* __restrict__ ei, int* __restrict__ cnt, int E) {
    int e = blockIdx.x * blockDim.x + threadIdx.x;
    if (e >= E) return;
    atomicAdd(&cnt[ei[E + e] * CPAD], 1);
}

// ---------------------------------------------------------------------------
// K2: single-block exclusive scan of deg -> rowptr
__global__ void scan_kernel(const int* __restrict__ cnt, int* __restrict__ rowptr,
                            int n, int total) {
    __shared__ int sums[1024];
    int t = threadIdx.x;
    int chunk = (n + 1023) / 1024;
    int lo = t * chunk, hi = min(lo + chunk, n);
    int s = 0;
    for (int i = lo; i < hi; ++i) s += cnt[i * CPAD];
    sums[t] = s;
    __syncthreads();
    for (int off = 1; off < 1024; off <<= 1) {
        int tmp = (t >= off) ? sums[t - off] : 0;
        __syncthreads();
        sums[t] += tmp;
        __syncthreads();
    }
    int run = sums[t] - s;   // exclusive prefix
    for (int i = lo; i < hi; ++i) {
        rowptr[i] = run;
        run += cnt[i * CPAD];
    }
    if (t == 0) rowptr[n] = total;
}

// K2b: seed padded cursors from rowptr
__global__ void posinit_kernel(const int* __restrict__ rowptr, int* __restrict__ pos, int n) {
    int i = blockIdx.x * blockDim.x + threadIdx.x;
    if (i < n) pos[i * CPAD] = rowptr[i];
}

// ---------------------------------------------------------------------------
// K3: scatter edges into dst-grouped CSR; entry = (src, edot1, edot2, 0)
__global__ void scatter_kernel(const int* __restrict__ ei, const float* __restrict__ ea,
                               const float* __restrict__ cvec, int* __restrict__ pos,
                               int* __restrict__ csr, int E) {
    int e = blockIdx.x * blockDim.x + threadIdx.x;
    if (e >= E) return;
    int s = ei[e], d = ei[E + e];
    float2 v = ((const float2*)ea)[e];
    float d1 = cvec[0] * v.x + cvec[1] * v.y;
    float d2 = cvec[2] * v.x + cvec[3] * v.y;
    int k = atomicAdd(&pos[d * CPAD], 1);
    v4i entry = { s, __float_as_int(d1), __float_as_int(d2), 0 };
    __builtin_nontemporal_store(entry, (v4i*)&csr[(size_t)k * 4]);
}

// ---------------------------------------------------------------------------
// K4: hs[i] = x[i]·vs, hd[i] = x[i]·vd over 64-dim x. One wave per node.
__global__ void hshd64_kernel(const float* __restrict__ x, const float* __restrict__ vs,
                              const float* __restrict__ vd, float* __restrict__ hs,
                              float* __restrict__ hd, int n) {
    int w = (blockIdx.x * blockDim.x + threadIdx.x) >> 6;
    int lane = threadIdx.x & 63;
    if (w >= n) return;
    float xv = x[(size_t)w * 64 + lane];
    float ss = xv * vs[lane];
    float sd = xv * vd[lane];
    for (int off = 32; off; off >>= 1) {
        ss += __shfl_xor(ss, off);
        sd += __shfl_xor(sd, off);
    }
    if (lane == 0) { hs[w] = ss; hd[w] = sd; }
}

// ---------------------------------------------------------------------------
// K5: fused GAT aggregation over a 64-dim feature matrix (layer 1: feat = x).
// t[dst] = sum_e softmax(logit)_e * feat[src_e]  (incl. analytic self-loop).
// One wave per node; 4 edges in flight (quarter-wave float4 groups).
__global__ __launch_bounds__(256) void agg64_kernel(
        const int* __restrict__ rowptr, const int4* __restrict__ csr,
        const float* __restrict__ hs, const float* __restrict__ hd,
        const float* __restrict__ feat, float* __restrict__ t_out, int n) {
    int w = (blockIdx.x * blockDim.x + threadIdx.x) >> 6;
    int lane = threadIdx.x & 63;
    if (w >= n) return;
    int beg = rowptr[w], end = rowptr[w + 1];
    int len = end - beg;
    float hdv = hd[w], hsw = hs[w];
    int g = lane >> 4;      // 4 groups
    int c16 = lane & 15;    // float4 index within 64-wide row
    float4 acc = make_float4(0.f, 0.f, 0.f, 0.f);
    float m, scale, lself;

    if (len <= 64) {
        bool valid = lane < len;
        int4 c4 = valid ? csr[beg + lane] : make_int4(0, 0, 0, 0);
        float ed = valid ? __int_as_float(c4.y) : 0.f;
        float l = hs[c4.x] + hdv + ed;
        l = (l >= 0.f) ? l : 0.2f * l;
        float mymax = valid ? l : -1e30f;
        float edsum = ed;
        for (int off = 32; off; off >>= 1) {
            mymax = fmaxf(mymax, __shfl_xor(mymax, off));
            edsum += __shfl_xor(edsum, off);
        }
        lself = hsw + hdv + edsum / fmaxf((float)len, 1.0f);
        lself = (lself >= 0.f) ? lself : 0.2f * lself;
        m = fmaxf(mymax, lself);
        float p = valid ? __expf(l - m) : 0.f;
        float psum = p;
        for (int off = 32; off; off >>= 1) psum += __shfl_xor(psum, off);
        psum += __expf(lself - m);
        scale = 1.f / (psum + 1e-16f);
        float pn = p * scale;
        int src = c4.x;
        for (int j = g; j < len; j += 4) {
            float a = __shfl(pn, j);
            int sj = __shfl(src, j);
            const float4 hv = *(const float4*)&feat[(size_t)sj * 64 + c16 * 4];
            acc.x += a * hv.x; acc.y += a * hv.y; acc.z += a * hv.z; acc.w += a * hv.w;
        }
    } else {
        float mymax = -1e30f, edsum = 0.f;
        for (int base = beg; base < end; base += 64) {
            int k = base + lane;
            if (k < end) {
                int4 c4 = csr[k];
                float ed = __int_as_float(c4.y);
                edsum += ed;
                float l = hs[c4.x] + hdv + ed;
                l = (l >= 0.f) ? l : 0.2f * l;
                mymax = fmaxf(mymax, l);
            }
        }
        for (int off = 32; off; off >>= 1) {
            mymax = fmaxf(mymax, __shfl_xor(mymax, off));
            edsum += __shfl_xor(edsum, off);
        }
        lself = hsw + hdv + edsum / fmaxf((float)len, 1.0f);
        lself = (lself >= 0.f) ? lself : 0.2f * lself;
        m = fmaxf(mymax, lself);
        float psum = 0.f;
        for (int base = beg; base < end; base += 64) {
            int k = base + lane;
            if (k < end) {
                int4 c4 = csr[k];
                float l = hs[c4.x] + hdv + __int_as_float(c4.y);
                l = (l >= 0.f) ? l : 0.2f * l;
                psum += __expf(l - m);
            }
        }
        for (int off = 32; off; off >>= 1) psum += __shfl_xor(psum, off);
        psum += __expf(lself - m);
        scale = 1.f / (psum + 1e-16f);
        for (int base = beg; base < end; base += 64) {
            int k = base + lane;
            float pn = 0.f; int src = 0;
            if (k < end) {
                int4 c4 = csr[k];
                float l = hs[c4.x] + hdv + __int_as_float(c4.y);
                l = (l >= 0.f) ? l : 0.2f * l;
                pn = __expf(l - m) * scale;
                src = c4.x;
            }
            int cl = min(end - base, 64);
            for (int j = g; j < cl; j += 4) {
                float a = __shfl(pn, j);
                int sj = __shfl(src, j);
                const float4 hv = *(const float4*)&feat[(size_t)sj * 64 + c16 * 4];
                acc.x += a * hv.x; acc.y += a * hv.y; acc.z += a * hv.z; acc.w += a * hv.w;
            }
        }
    }
    if (g == 0) {  // self-loop
        float a = __expf(lself - m) * scale;
        const float4 hv = *(const float4*)&feat[(size_t)w * 64 + c16 * 4];
        acc.x += a * hv.x; acc.y += a * hv.y; acc.z += a * hv.z; acc.w += a * hv.w;
    }
    // combine 4 group partials into lanes 0..15
    float4 p1, p2, p3;
    p1.x = __shfl(acc.x, c16 + 16); p1.y = __shfl(acc.y, c16 + 16);
    p1.z = __shfl(acc.z, c16 + 16); p1.w = __shfl(acc.w, c16 + 16);
    p2.x = __shfl(acc.x, c16 + 32); p2.y = __shfl(acc.y, c16 + 32);
    p2.z = __shfl(acc.z, c16 + 32); p2.w = __shfl(acc.w, c16 + 32);
    p3.x = __shfl(acc.x, c16 + 48); p3.y = __shfl(acc.y, c16 + 48);
    p3.z = __shfl(acc.z, c16 + 48); p3.w = __shfl(acc.w, c16 + 48);
    if (lane < 16) {
        float4 o;
        o.x = acc.x + p1.x + p2.x + p3.x;
        o.y = acc.y + p1.y + p2.y + p3.y;
        o.z = acc.z + p1.z + p2.z + p3.z;
        o.w = acc.w + p1.w + p2.w + p3.w;
        *(float4*)&t_out[(size_t)w * 64 + c16 * 4] = o;
    }
}

// ---------------------------------------------------------------------------
// K6: fused GAT aggregation over 128-dim features (layer 2: feat = out1).
__global__ __launch_bounds__(256) void agg128_kernel(
        const int* __restrict__ rowptr, const int4* __restrict__ csr,
        const float* __restrict__ hs, const float* __restrict__ hd,
        const float* __restrict__ feat, float* __restrict__ t_out, int n) {
    int w = (blockIdx.x * blockDim.x + threadIdx.x) >> 6;
    int lane = threadIdx.x & 63;
    if (w >= n) return;
    int beg = rowptr[w], end = rowptr[w + 1];
    int len = end - beg;
    float hdv = hd[w], hsw = hs[w];
    int half = lane >> 5;
    int col = lane & 31;
    float4 acc = make_float4(0.f, 0.f, 0.f, 0.f);
    float m, scale, lself;

    if (len <= 64) {
        bool valid = lane < len;
        int4 c4 = valid ? csr[beg + lane] : make_int4(0, 0, 0, 0);
        float ed = valid ? __int_as_float(c4.z) : 0.f;
        float l = hs[c4.x] + hdv + ed;
        l = (l >= 0.f) ? l : 0.2f * l;
        float mymax = valid ? l : -1e30f;
        float edsum = ed;
        for (int off = 32; off; off >>= 1) {
            mymax = fmaxf(mymax, __shfl_xor(mymax, off));
            edsum += __shfl_xor(edsum, off);
        }
        lself = hsw + hdv + edsum / fmaxf((float)len, 1.0f);
        lself = (lself >= 0.f) ? lself : 0.2f * lself;
        m = fmaxf(mymax, lself);
        float p = valid ? __expf(l - m) : 0.f;
        float psum = p;
        for (int off = 32; off; off >>= 1) psum += __shfl_xor(psum, off);
        psum += __expf(lself - m);
        scale = 1.f / (psum + 1e-16f);
        float pn = p * scale;
        int src = c4.x;
        for (int j = half; j < len; j += 2) {
            float a = __shfl(pn, j);
            int sj = __shfl(src, j);
            const float4 hv = *(const float4*)&feat[(size_t)sj * H_DIM + col * 4];
            acc.x += a * hv.x; acc.y += a * hv.y; acc.z += a * hv.z; acc.w += a * hv.w;
        }
    } else {
        float mymax = -1e30f, edsum = 0.f;
        for (int base = beg; base < end; base += 64) {
            int k = base + lane;
            if (k < end) {
                int4 c4 = csr[k];
                float ed = __int_as_float(c4.z);
                edsum += ed;
                float l = hs[c4.x] + hdv + ed;
                l = (l >= 0.f) ? l : 0.2f * l;
                mymax = fmaxf(mymax, l);
            }
        }
        for (int off = 32; off; off >>= 1) {
            mymax = fmaxf(mymax, __shfl_xor(mymax, off));
            edsum += __shfl_xor(edsum, off);
        }
        lself = hsw + hdv + edsum / fmaxf((float)len, 1.0f);
        lself = (lself >= 0.f) ? lself : 0.2f * lself;
        m = fmaxf(mymax, lself);
        float psum = 0.f;
        for (int base = beg; base < end; base += 64) {
            int k = base + lane;
            if (k < end) {
                int4 c4 = csr[k];
                float l = hs[c4.x] + hdv + __int_as_float(c4.z);
                l = (l >= 0.f) ? l : 0.2f * l;
                psum += __expf(l - m);
            }
        }
        for (int off = 32; off; off >>= 1) psum += __shfl_xor(psum, off);
        psum += __expf(lself - m);
        scale = 1.f / (psum + 1e-16f);
        for (int base = beg; base < end; base += 64) {
            int k = base + lane;
            float pn = 0.f; int src = 0;
            if (k < end) {
                int4 c4 = csr[k];
                float l = hs[c4.x] + hdv + __int_as_float(c4.z);
                l = (l >= 0.f) ? l : 0.2f * l;
                pn = __expf(l - m) * scale;
                src = c4.x;
            }
            int cl = min(end - base, 64);
            for (int j = half; j < cl; j += 2) {
                float a = __shfl(pn, j);
                int sj = __shfl(src, j);
                const float4 hv = *(const float4*)&feat[(size_t)sj * H_DIM + col * 4];
                acc.x += a * hv.x; acc.y += a * hv.y; acc.z += a * hv.z; acc.w += a * hv.w;
            }
        }
    }
    if (half == 0) {  // self-loop
        float a = __expf(lself - m) * scale;
        const float4 hv = *(const float4*)&feat[(size_t)w * H_DIM + col * 4];
        acc.x += a * hv.x; acc.y += a * hv.y; acc.z += a * hv.z; acc.w += a * hv.w;
    }
    float4 oth;
    oth.x = __shfl(acc.x, col + 32);
    oth.y = __shfl(acc.y, col + 32);
    oth.z = __shfl(acc.z, col + 32);
    oth.w = __shfl(acc.w, col + 32);
    if (half == 0) {
        float4 o;
        o.x = acc.x + oth.x; o.y = acc.y + oth.y;
        o.z = acc.z + oth.z; o.w = acc.w + oth.w;
        *(float4*)&t_out[(size_t)w * H_DIM + col * 4] = o;
    }
}

// ---------------------------------------------------------------------------
// K7: out = relu(T @ W + b); optional epilogue hs/hd for the NEXT layer
// (hs[i] = out[i]·vs, hd[i] = out[i]·vd). 32 rows/block, 4x4 per thread.
template <int FIN, bool DO_HSHD>
__global__ __launch_bounds__(256) void gemm_kernel(const float* __restrict__ X,
                                                   const float* __restrict__ W,
                                                   const float* __restrict__ bias,
                                                   const float* __restrict__ vs,
                                                   const float* __restrict__ vd,
                                                   float* __restrict__ Hout,
                                                   float* __restrict__ hs,
                                                   float* __restrict__ hd, int n) {
    __shared__ float xs[32 * FIN];
    int tid = threadIdx.x;
    int r0 = blockIdx.x * 32;
    for (int idx = tid; idx < 32 * FIN; idx += 256) {
        int r = idx / FIN, k = idx - r * FIN;
        int row = r0 + r;
        xs[idx] = (row < n) ? X[(size_t)row * FIN + k] : 0.0f;
    }
    __syncthreads();
    int tcol = tid & 31;   // cols 4*tcol .. +3
    int trow = tid >> 5;   // rows 4*trow .. +3
    float acc[4][4] = {{0.f}};
    const float* wp = W + tcol * 4;
    const float* x0p = &xs[(trow * 4 + 0) * FIN];
    const float* x1p = &xs[(trow * 4 + 1) * FIN];
    const float* x2p = &xs[(trow * 4 + 2) * FIN];
    const float* x3p = &xs[(trow * 4 + 3) * FIN];
#pragma unroll 8
    for (int k = 0; k < FIN; ++k) {
        float4 w4 = *(const float4*)(wp + k * H_DIM);
        float x0 = x0p[k], x1 = x1p[k], x2 = x2p[k], x3 = x3p[k];
        acc[0][0] += x0 * w4.x; acc[0][1] += x0 * w4.y; acc[0][2] += x0 * w4.z; acc[0][3] += x0 * w4.w;
        acc[1][0] += x1 * w4.x; acc[1][1] += x1 * w4.y; acc[1][2] += x1 * w4.z; acc[1][3] += x1 * w4.w;
        acc[2][0] += x2 * w4.x; acc[2][1] += x2 * w4.y; acc[2][2] += x2 * w4.z; acc[2][3] += x2 * w4.w;
        acc[3][0] += x3 * w4.x; acc[3][1] += x3 * w4.y; acc[3][2] += x3 * w4.z; acc[3][3] += x3 * w4.w;
    }
    float4 b4 = *(const float4*)&bias[tcol * 4];
    float4 vs4, vd4;
    if (DO_HSHD) {
        vs4 = *(const float4*)&vs[tcol * 4];
        vd4 = *(const float4*)&vd[tcol * 4];
    }
#pragma unroll
    for (int r = 0; r < 4; ++r) {
        int row = r0 + trow * 4 + r;
        float4 o;
        o.x = fmaxf(acc[r][0] + b4.x, 0.f);
        o.y = fmaxf(acc[r][1] + b4.y, 0.f);
        o.z = fmaxf(acc[r][2] + b4.z, 0.f);
        o.w = fmaxf(acc[r][3] + b4.w, 0.f);
        if (row < n) *(float4*)&Hout[(size_t)row * H_DIM + tcol * 4] = o;
        if (DO_HSHD) {
            float ss = o.x * vs4.x + o.y * vs4.y + o.z * vs4.z + o.w * vs4.w;
            float sd = o.x * vd4.x + o.y * vd4.y + o.z * vd4.z + o.w * vd4.w;
            for (int off = 16; off; off >>= 1) {
                ss += __shfl_xor(ss, off);
                sd += __shfl_xor(sd, off);
            }
            if (tcol == 0 && row < n) { hs[row] = ss; hd[row] = sd; }
        }
    }
}

// ---------------------------------------------------------------------------
// K8: column sums of h (for mean pooling)
__global__ void pool_kernel(const float* __restrict__ hmat, float* __restrict__ pooled,
                            int n) {
    __shared__ float red[256];
    int col = threadIdx.x & 127;
    int half = threadIdx.x >> 7;
    int rows_per_block = (n + gridDim.x - 1) / gridDim.x;
    int r0 = blockIdx.x * rows_per_block;
    int r1 = min(r0 + rows_per_block, n);
    float s = 0.f;
    for (int r = r0 + half; r < r1; r += 2) s += hmat[(size_t)r * H_DIM + col];
    red[threadIdx.x] = s;
    __syncthreads();
    if (half == 0) atomicAdd(&pooled[col], red[threadIdx.x] + red[threadIdx.x + 128]);
}

// ---------------------------------------------------------------------------
// K9: out = tanh(mean(h) @ Wfc + bfc)
__global__ void final_kernel(const float* __restrict__ pooled, const float* __restrict__ Wfc,
                             const float* __restrict__ bfc, float* __restrict__ out, int n) {
    int t = threadIdx.x;
    if (t >= 16) return;
    float inv_n = 1.0f / (float)n;
    float s = 0.f;
    for (int j = 0; j < 128; ++j) s += pooled[j] * inv_n * Wfc[j * 16 + t];
    out[t] = tanhf(s + bfc[t]);
}

// ---------------------------------------------------------------------------
extern "C" void kernel_launch(void* const* d_in, const int* in_sizes, int n_in,
                              void* d_out, int out_size, void* d_ws, size_t ws_size,
                              hipStream_t stream) {
    const float* x   = (const float*)d_in[0];
    const int*   ei  = (const int*)d_in[1];
    const float* ea  = (const float*)d_in[2];
    const float* W1  = (const float*)d_in[3];
    const float* We1 = (const float*)d_in[4];
    const float* as1 = (const float*)d_in[5];
    const float* ad1 = (const float*)d_in[6];
    const float* ae1 = (const float*)d_in[7];
    const float* b1  = (const float*)d_in[8];
    const float* W2  = (const float*)d_in[9];
    const float* We2 = (const float*)d_in[10];
    const float* as2 = (const float*)d_in[11];
    const float* ad2 = (const float*)d_in[12];
    const float* ae2 = (const float*)d_in[13];
    const float* b2  = (const float*)d_in[14];
    const float* Wfc = (const float*)d_in[15];
    const float* bfc = (const float*)d_in[16];
    float* out = (float*)d_out;

    const int n = in_sizes[0] / 64;      // 50000
    const int E = in_sizes[1] / 2;       // 1600000

    // workspace layout (float units, 256B-aligned blocks)
    size_t o = 0;
    auto alloc = [&](size_t count) { size_t r = o; o += (count + 63) & ~(size_t)63; return r; };
    size_t o_cnt    = alloc((size_t)n * CPAD);   // int, padded
    size_t o_pos    = alloc((size_t)n * CPAD);   // int, padded
    size_t o_rowptr = alloc(n + 1);              // int
    size_t o_csr    = alloc(4 * (size_t)E);      // int4 per edge
    size_t o_hs     = alloc(n);
    size_t o_hd     = alloc(n);
    size_t o_bufA   = alloc((size_t)n * H_DIM);  // out1 / out2
    size_t o_bufB   = alloc((size_t)n * H_DIM);  // t1 (64-dim) then t2 (128-dim)
    size_t o_c      = alloc(4);
    size_t o_vs1    = alloc(64);
    size_t o_vd1    = alloc(64);
    size_t o_vs2    = alloc(128);
    size_t o_vd2    = alloc(128);
    size_t o_pool   = alloc(128);
    (void)ws_size;  // ~79 MB needed

    float* wsf = (float*)d_ws;
    hipMemsetAsync(wsf + o_cnt, 0, (size_t)n * CPAD * sizeof(int), stream);
    hipMemsetAsync(wsf + o_pool, 0, 128 * sizeof(float), stream);

    prep_kernel<<<1, 256, 0, stream>>>(We1, ae1, We2, ae2, W1, as1, ad1, W2, as2, ad2,
        wsf + o_c, wsf + o_vs1, wsf + o_vd1, wsf + o_vs2, wsf + o_vd2);
    deg_kernel<<<(E + 255) / 256, 256, 0, stream>>>(ei, (int*)(wsf + o_cnt), E);
    scan_kernel<<<1, 1024, 0, stream>>>((int*)(wsf + o_cnt), (int*)(wsf + o_rowptr), n, E);
    posinit_kernel<<<(n + 255) / 256, 256, 0, stream>>>((int*)(wsf + o_rowptr),
        (int*)(wsf + o_pos), n);
    scatter_kernel<<<(E + 255) / 256, 256, 0, stream>>>(ei, ea, wsf + o_c,
        (int*)(wsf + o_pos), (int*)(wsf + o_csr), E);

    int wgrid = (n + 3) / 4;  // 4 waves (nodes) per 256-thread block

    // ---- layer 1 (aggregate x, then GEMM) ----
    hshd64_kernel<<<wgrid, 256, 0, stream>>>(x, wsf + o_vs1, wsf + o_vd1,
        wsf + o_hs, wsf + o_hd, n);
    agg64_kernel<<<wgrid, 256, 0, stream>>>((int*)(wsf + o_rowptr), (const int4*)(wsf + o_csr),
        wsf + o_hs, wsf + o_hd, x, wsf + o_bufB, n);
    gemm_kernel<64, true><<<(n + 31) / 32, 256, 0, stream>>>(wsf + o_bufB, W1, b1,
        wsf + o_vs2, wsf + o_vd2, wsf + o_bufA, wsf + o_hs, wsf + o_hd, n);

    // ---- layer 2 (aggregate out1, then GEMM) ----
    agg128_kernel<<<wgrid, 256, 0, stream>>>((int*)(wsf + o_rowptr), (const int4*)(wsf + o_csr),
        wsf + o_hs, wsf + o_hd, wsf + o_bufA, wsf + o_bufB, n);
    gemm_kernel<128, false><<<(n + 31) / 32, 256, 0, stream>>>(wsf + o_bufB, W2, b2,
        nullptr, nullptr, wsf + o_bufA, nullptr, nullptr, n);

    // ---- pooling + head ----
    pool_kernel<<<256, 256, 0, stream>>>(wsf + o_bufA, wsf + o_pool, n);
    final_kernel<<<1, 64, 0, stream>>>(wsf + o_pool, Wfc, bfc, out, n);
}

// Round 4
// 440.361 us; speedup vs baseline: 2.5538x; 1.4855x over previous
//
#include <hip/hip_runtime.h>
#include <math.h>

// Problem constants: N=50000, E=1600000, F=64, H=128, ED=2, A=16
#define H_DIM 128
#define BWID 128      // dsts per bucket (bucket = dst >> 7)
#define BMAX 512      // max buckets (n <= 65536)
#define CHUNK 4096    // edges per block in count/bin

typedef int v4i __attribute__((ext_vector_type(4)));

// ---------------------------------------------------------------------------
// K0: tiny precomputes in one block.
//   c[0..3]  = We^T @ a_edge (both layers)
//   vs1/vd1  = W1 @ a_s1 / W1 @ a_d1   (64 each)
//   vs2/vd2  = W2 @ a_s2 / W2 @ a_d2   (128 each)
__global__ void prep_kernel(const float* __restrict__ We1, const float* __restrict__ ae1,
                            const float* __restrict__ We2, const float* __restrict__ ae2,
                            const float* __restrict__ W1, const float* __restrict__ as1,
                            const float* __restrict__ ad1,
                            const float* __restrict__ W2, const float* __restrict__ as2,
                            const float* __restrict__ ad2,
                            float* __restrict__ c, float* __restrict__ vs1,
                            float* __restrict__ vd1, float* __restrict__ vs2,
                            float* __restrict__ vd2) {
    int t = threadIdx.x;  // 256 threads
    if (t < 64) {
        float s = 0.f, d = 0.f;
        for (int h = 0; h < 128; ++h) {
            float w = W1[t * 128 + h];
            s += w * as1[h];
            d += w * ad1[h];
        }
        vs1[t] = s; vd1[t] = d;
    } else if (t < 192) {
        int k = t - 64;
        float s = 0.f, d = 0.f;
        for (int h = 0; h < 128; ++h) {
            float w = W2[k * 128 + h];
            s += w * as2[h];
            d += w * ad2[h];
        }
        vs2[k] = s; vd2[k] = d;
    } else {
        int l = t - 192;  // lane of wave 3
        float a1x = ae1[l], a1y = ae1[l + 64];
        float a2x = ae2[l], a2y = ae2[l + 64];
        float v0 = We1[l] * a1x + We1[l + 64] * a1y;
        float v1 = We1[128 + l] * a1x + We1[192 + l] * a1y;
        float v2 = We2[l] * a2x + We2[l + 64] * a2y;
        float v3 = We2[128 + l] * a2x + We2[192 + l] * a2y;
        for (int off = 32; off; off >>= 1) {
            v0 += __shfl_xor(v0, off);
            v1 += __shfl_xor(v1, off);
            v2 += __shfl_xor(v2, off);
            v3 += __shfl_xor(v3, off);
        }
        if (l == 0) { c[0] = v0; c[1] = v1; c[2] = v2; c[3] = v3; }
    }
}

// ---------------------------------------------------------------------------
// K1: bucket histogram (LDS pre-aggregated; ~B atomics per block)
__global__ __launch_bounds__(256) void count_kernel(const int* __restrict__ ei,
                                                    int* __restrict__ gcnt, int E, int B) {
    __shared__ int hist[BMAX];
    int tid = threadIdx.x;
    for (int i = tid; i < B; i += 256) hist[i] = 0;
    __syncthreads();
    int lo = blockIdx.x * CHUNK, hi = min(lo + CHUNK, E);
    for (int e = lo + tid; e < hi; e += 256)
        atomicAdd(&hist[ei[E + e] >> 7], 1);
    __syncthreads();
    for (int i = tid; i < B; i += 256)
        if (hist[i]) atomicAdd(&gcnt[i], hist[i]);
}

// ---------------------------------------------------------------------------
// K2: scan bucket counts -> bstart (excl prefix), seed gcur, write tails
__global__ void bscan_kernel(const int* __restrict__ gcnt, int* __restrict__ bstart,
                             int* __restrict__ gcur, int* __restrict__ rowptr,
                             int B, int n, int E) {
    __shared__ int s[BMAX];
    int t = threadIdx.x;  // 512 threads
    int v0 = (t < B) ? gcnt[t] : 0;
    s[t] = v0;
    __syncthreads();
    for (int off = 1; off < BMAX; off <<= 1) {
        int v = (t >= off) ? s[t - off] : 0;
        __syncthreads();
        s[t] += v;
        __syncthreads();
    }
    if (t < B) {
        int excl = s[t] - v0;
        bstart[t] = excl;
        gcur[t] = excl;
    }
    if (t == 0) { bstart[B] = E; rowptr[n] = E; }
}

// ---------------------------------------------------------------------------
// K3: bin edges by bucket. Per-block LDS histogram -> one global reservation
// per (block,bucket) -> dense ~160B runs per bucket (L2 line merging works).
// binned entry = (src, dst, edot1, edot2)
__global__ __launch_bounds__(256) void bin_kernel(const int* __restrict__ ei,
                                                  const float* __restrict__ ea,
                                                  const float* __restrict__ cvec,
                                                  int* __restrict__ gcur,
                                                  int4* __restrict__ binned, int E, int B) {
    __shared__ int cnt[BMAX];
    __shared__ int base[BMAX];
    int tid = threadIdx.x;
    for (int i = tid; i < B; i += 256) cnt[i] = 0;
    __syncthreads();
    int lo = blockIdx.x * CHUNK, hi = min(lo + CHUNK, E);
    for (int e = lo + tid; e < hi; e += 256)
        atomicAdd(&cnt[ei[E + e] >> 7], 1);
    __syncthreads();
    for (int i = tid; i < B; i += 256) {
        int c = cnt[i];
        base[i] = c ? atomicAdd(&gcur[i], c) : 0;
        cnt[i] = 0;  // reuse as local cursor
    }
    __syncthreads();
    float c0 = cvec[0], c1 = cvec[1], c2 = cvec[2], c3 = cvec[3];
    for (int e = lo + tid; e < hi; e += 256) {
        int s = ei[e], d = ei[E + e];
        float2 v = ((const float2*)ea)[e];
        float d1 = c0 * v.x + c1 * v.y;
        float d2 = c2 * v.x + c3 * v.y;
        int b = d >> 7;
        int loc = atomicAdd(&cnt[b], 1);
        binned[(size_t)(base[b] + loc)] = make_int4(s, d, __float_as_int(d1), __float_as_int(d2));
    }
}

// ---------------------------------------------------------------------------
// K4: one block per bucket: per-dst count + LDS scan -> rowptr, then scatter
// into final dst-grouped CSR. All writes land in this bucket's exclusive,
// L2-resident ~64KB slot range -> full-line writebacks.
// csr entry = (src, edot1, edot2, 0)
__global__ __launch_bounds__(256) void build_kernel(const int* __restrict__ bstart,
                                                    const int4* __restrict__ binned,
                                                    int* __restrict__ rowptr,
                                                    int4* __restrict__ csr, int n) {
    __shared__ int cnt[BWID];
    __shared__ int sc[BWID];
    __shared__ int cur[BWID];
    int b = blockIdx.x, tid = threadIdx.x;
    int d0 = b << 7;
    int lo = bstart[b], hi = bstart[b + 1];
    if (tid < BWID) cnt[tid] = 0;
    __syncthreads();
    for (int k = lo + tid; k < hi; k += 256)
        atomicAdd(&cnt[binned[k].y & (BWID - 1)], 1);
    __syncthreads();
    if (tid < BWID) sc[tid] = cnt[tid];
    __syncthreads();
    for (int off = 1; off < BWID; off <<= 1) {
        int v = (tid < BWID && tid >= off) ? sc[tid - off] : 0;
        __syncthreads();
        if (tid < BWID) sc[tid] += v;
        __syncthreads();
    }
    if (tid < BWID) {
        int excl = sc[tid] - cnt[tid];
        cur[tid] = lo + excl;
        int d = d0 + tid;
        if (d < n) rowptr[d] = lo + excl;
    }
    __syncthreads();
    for (int k = lo + tid; k < hi; k += 256) {
        int4 e = binned[k];
        int slot = atomicAdd(&cur[e.y & (BWID - 1)], 1);
        csr[slot] = make_int4(e.x, e.z, e.w, 0);
    }
}

// ---------------------------------------------------------------------------
// K5: hs[i] = x[i]·vs, hd[i] = x[i]·vd over 64-dim x. One wave per node.
__global__ void hshd64_kernel(const float* __restrict__ x, const float* __restrict__ vs,
                              const float* __restrict__ vd, float* __restrict__ hs,
                              float* __restrict__ hd, int n) {
    int w = (blockIdx.x * blockDim.x + threadIdx.x) >> 6;
    int lane = threadIdx.x & 63;
    if (w >= n) return;
    float xv = x[(size_t)w * 64 + lane];
    float ss = xv * vs[lane];
    float sd = xv * vd[lane];
    for (int off = 32; off; off >>= 1) {
        ss += __shfl_xor(ss, off);
        sd += __shfl_xor(sd, off);
    }
    if (lane == 0) { hs[w] = ss; hd[w] = sd; }
}

// ---------------------------------------------------------------------------
// K6: fused GAT aggregation over 64-dim features (layer 1: feat = x).
__global__ __launch_bounds__(256) void agg64_kernel(
        const int* __restrict__ rowptr, const int4* __restrict__ csr,
        const float* __restrict__ hs, const float* __restrict__ hd,
        const float* __restrict__ feat, float* __restrict__ t_out, int n) {
    int w = (blockIdx.x * blockDim.x + threadIdx.x) >> 6;
    int lane = threadIdx.x & 63;
    if (w >= n) return;
    int beg = rowptr[w], end = rowptr[w + 1];
    int len = end - beg;
    float hdv = hd[w], hsw = hs[w];
    int g = lane >> 4;      // 4 groups
    int c16 = lane & 15;    // float4 index within 64-wide row
    float4 acc = make_float4(0.f, 0.f, 0.f, 0.f);
    float m, scale, lself;

    if (len <= 64) {
        bool valid = lane < len;
        int4 c4 = valid ? csr[beg + lane] : make_int4(0, 0, 0, 0);
        float ed = valid ? __int_as_float(c4.y) : 0.f;
        float l = hs[c4.x] + hdv + ed;
        l = (l >= 0.f) ? l : 0.2f * l;
        float mymax = valid ? l : -1e30f;
        float edsum = ed;
        for (int off = 32; off; off >>= 1) {
            mymax = fmaxf(mymax, __shfl_xor(mymax, off));
            edsum += __shfl_xor(edsum, off);
        }
        lself = hsw + hdv + edsum / fmaxf((float)len, 1.0f);
        lself = (lself >= 0.f) ? lself : 0.2f * lself;
        m = fmaxf(mymax, lself);
        float p = valid ? __expf(l - m) : 0.f;
        float psum = p;
        for (int off = 32; off; off >>= 1) psum += __shfl_xor(psum, off);
        psum += __expf(lself - m);
        scale = 1.f / (psum + 1e-16f);
        float pn = p * scale;
        int src = c4.x;
        for (int j = g; j < len; j += 4) {
            float a = __shfl(pn, j);
            int sj = __shfl(src, j);
            const float4 hv = *(const float4*)&feat[(size_t)sj * 64 + c16 * 4];
            acc.x += a * hv.x; acc.y += a * hv.y; acc.z += a * hv.z; acc.w += a * hv.w;
        }
    } else {
        float mymax = -1e30f, edsum = 0.f;
        for (int base = beg; base < end; base += 64) {
            int k = base + lane;
            if (k < end) {
                int4 c4 = csr[k];
                float ed = __int_as_float(c4.y);
                edsum += ed;
                float l = hs[c4.x] + hdv + ed;
                l = (l >= 0.f) ? l : 0.2f * l;
                mymax = fmaxf(mymax, l);
            }
        }
        for (int off = 32; off; off >>= 1) {
            mymax = fmaxf(mymax, __shfl_xor(mymax, off));
            edsum += __shfl_xor(edsum, off);
        }
        lself = hsw + hdv + edsum / fmaxf((float)len, 1.0f);
        lself = (lself >= 0.f) ? lself : 0.2f * lself;
        m = fmaxf(mymax, lself);
        float psum = 0.f;
        for (int base = beg; base < end; base += 64) {
            int k = base + lane;
            if (k < end) {
                int4 c4 = csr[k];
                float l = hs[c4.x] + hdv + __int_as_float(c4.y);
                l = (l >= 0.f) ? l : 0.2f * l;
                psum += __expf(l - m);
            }
        }
        for (int off = 32; off; off >>= 1) psum += __shfl_xor(psum, off);
        psum += __expf(lself - m);
        scale = 1.f / (psum + 1e-16f);
        for (int base = beg; base < end; base += 64) {
            int k = base + lane;
            float pn = 0.f; int src = 0;
            if (k < end) {
                int4 c4 = csr[k];
                float l = hs[c4.x] + hdv + __int_as_float(c4.y);
                l = (l >= 0.f) ? l : 0.2f * l;
                pn = __expf(l - m) * scale;
                src = c4.x;
            }
            int cl = min(end - base, 64);
            for (int j = g; j < cl; j += 4) {
                float a = __shfl(pn, j);
                int sj = __shfl(src, j);
                const float4 hv = *(const float4*)&feat[(size_t)sj * 64 + c16 * 4];
                acc.x += a * hv.x; acc.y += a * hv.y; acc.z += a * hv.z; acc.w += a * hv.w;
            }
        }
    }
    if (g == 0) {  // self-loop
        float a = __expf(lself - m) * scale;
        const float4 hv = *(const float4*)&feat[(size_t)w * 64 + c16 * 4];
        acc.x += a * hv.x; acc.y += a * hv.y; acc.z += a * hv.z; acc.w += a * hv.w;
    }
    // combine 4 group partials into lanes 0..15
    float4 p1, p2, p3;
    p1.x = __shfl(acc.x, c16 + 16); p1.y = __shfl(acc.y, c16 + 16);
    p1.z = __shfl(acc.z, c16 + 16); p1.w = __shfl(acc.w, c16 + 16);
    p2.x = __shfl(acc.x, c16 + 32); p2.y = __shfl(acc.y, c16 + 32);
    p2.z = __shfl(acc.z, c16 + 32); p2.w = __shfl(acc.w, c16 + 32);
    p3.x = __shfl(acc.x, c16 + 48); p3.y = __shfl(acc.y, c16 + 48);
    p3.z = __shfl(acc.z, c16 + 48); p3.w = __shfl(acc.w, c16 + 48);
    if (lane < 16) {
        float4 o;
        o.x = acc.x + p1.x + p2.x + p3.x;
        o.y = acc.y + p1.y + p2.y + p3.y;
        o.z = acc.z + p1.z + p2.z + p3.z;
        o.w = acc.w + p1.w + p2.w + p3.w;
        *(float4*)&t_out[(size_t)w * 64 + c16 * 4] = o;
    }
}

// ---------------------------------------------------------------------------
// K7: fused GAT aggregation over 128-dim features (layer 2: feat = out1).
__global__ __launch_bounds__(256) void agg128_kernel(
        const int* __restrict__ rowptr, const int4* __restrict__ csr,
        const float* __restrict__ hs, const float* __restrict__ hd,
        const float* __restrict__ feat, float* __restrict__ t_out, int n) {
    int w = (blockIdx.x * blockDim.x + threadIdx.x) >> 6;
    int lane = threadIdx.x & 63;
    if (w >= n) return;
    int beg = rowptr[w], end = rowptr[w + 1];
    int len = end - beg;
    float hdv = hd[w], hsw = hs[w];
    int half = lane >> 5;
    int col = lane & 31;
    float4 acc = make_float4(0.f, 0.f, 0.f, 0.f);
    float m, scale, lself;

    if (len <= 64) {
        bool valid = lane < len;
        int4 c4 = valid ? csr[beg + lane] : make_int4(0, 0, 0, 0);
        float ed = valid ? __int_as_float(c4.z) : 0.f;
        float l = hs[c4.x] + hdv + ed;
        l = (l >= 0.f) ? l : 0.2f * l;
        float mymax = valid ? l : -1e30f;
        float edsum = ed;
        for (int off = 32; off; off >>= 1) {
            mymax = fmaxf(mymax, __shfl_xor(mymax, off));
            edsum += __shfl_xor(edsum, off);
        }
        lself = hsw + hdv + edsum / fmaxf((float)len, 1.0f);
        lself = (lself >= 0.f) ? lself : 0.2f * lself;
        m = fmaxf(mymax, lself);
        float p = valid ? __expf(l - m) : 0.f;
        float psum = p;
        for (int off = 32; off; off >>= 1) psum += __shfl_xor(psum, off);
        psum += __expf(lself - m);
        scale = 1.f / (psum + 1e-16f);
        float pn = p * scale;
        int src = c4.x;
        for (int j = half; j < len; j += 2) {
            float a = __shfl(pn, j);
            int sj = __shfl(src, j);
            const float4 hv = *(const float4*)&feat[(size_t)sj * H_DIM + col * 4];
            acc.x += a * hv.x; acc.y += a * hv.y; acc.z += a * hv.z; acc.w += a * hv.w;
        }
    } else {
        float mymax = -1e30f, edsum = 0.f;
        for (int base = beg; base < end; base += 64) {
            int k = base + lane;
            if (k < end) {
                int4 c4 = csr[k];
                float ed = __int_as_float(c4.z);
                edsum += ed;
                float l = hs[c4.x] + hdv + ed;
                l = (l >= 0.f) ? l : 0.2f * l;
                mymax = fmaxf(mymax, l);
            }
        }
        for (int off = 32; off; off >>= 1) {
            mymax = fmaxf(mymax, __shfl_xor(mymax, off));
            edsum += __shfl_xor(edsum, off);
        }
        lself = hsw + hdv + edsum / fmaxf((float)len, 1.0f);
        lself = (lself >= 0.f) ? lself : 0.2f * lself;
        m = fmaxf(mymax, lself);
        float psum = 0.f;
        for (int base = beg; base < end; base += 64) {
            int k = base + lane;
            if (k < end) {
                int4 c4 = csr[k];
                float l = hs[c4.x] + hdv + __int_as_float(c4.z);
                l = (l >= 0.f) ? l : 0.2f * l;
                psum += __expf(l - m);
            }
        }
        for (int off = 32; off; off >>= 1) psum += __shfl_xor(psum, off);
        psum += __expf(lself - m);
        scale = 1.f / (psum + 1e-16f);
        for (int base = beg; base < end; base += 64) {
            int k = base + lane;
            float pn = 0.f; int src = 0;
            if (k < end) {
                int4 c4 = csr[k];
                float l = hs[c4.x] + hdv + __int_as_float(c4.z);
                l = (l >= 0.f) ? l : 0.2f * l;
                pn = __expf(l - m) * scale;
                src = c4.x;
            }
            int cl = min(end - base, 64);
            for (int j = half; j < cl; j += 2) {
                float a = __shfl(pn, j);
                int sj = __shfl(src, j);
                const float4 hv = *(const float4*)&feat[(size_t)sj * H_DIM + col * 4];
                acc.x += a * hv.x; acc.y += a * hv.y; acc.z += a * hv.z; acc.w += a * hv.w;
            }
        }
    }
    if (half == 0) {  // self-loop
        float a = __expf(lself - m) * scale;
        const float4 hv = *(const float4*)&feat[(size_t)w * H_DIM + col * 4];
        acc.x += a * hv.x; acc.y += a * hv.y; acc.z += a * hv.z; acc.w += a * hv.w;
    }
    float4 oth;
    oth.x = __shfl(acc.x, col + 32);
    oth.y = __shfl(acc.y, col + 32);
    oth.z = __shfl(acc.z, col + 32);
    oth.w = __shfl(acc.w, col + 32);
    if (half == 0) {
        float4 o;
        o.x = acc.x + oth.x; o.y = acc.y + oth.y;
        o.z = acc.z + oth.z; o.w = acc.w + oth.w;
        *(float4*)&t_out[(size_t)w * H_DIM + col * 4] = o;
    }
}

// ---------------------------------------------------------------------------
// K8: out = relu(T @ W + b); optional epilogue hs/hd for the NEXT layer.
template <int FIN, bool DO_HSHD>
__global__ __launch_bounds__(256) void gemm_kernel(const float* __restrict__ X,
                                                   const float* __restrict__ W,
                                                   const float* __restrict__ bias,
                                                   const float* __restrict__ vs,
                                                   const float* __restrict__ vd,
                                                   float* __restrict__ Hout,
                                                   float* __restrict__ hs,
                                                   float* __restrict__ hd, int n) {
    __shared__ float xs[32 * FIN];
    int tid = threadIdx.x;
    int r0 = blockIdx.x * 32;
    for (int idx = tid; idx < 32 * FIN; idx += 256) {
        int r = idx / FIN, k = idx - r * FIN;
        int row = r0 + r;
        xs[idx] = (row < n) ? X[(size_t)row * FIN + k] : 0.0f;
    }
    __syncthreads();
    int tcol = tid & 31;   // cols 4*tcol .. +3
    int trow = tid >> 5;   // rows 4*trow .. +3
    float acc[4][4] = {{0.f}};
    const float* wp = W + tcol * 4;
    const float* x0p = &xs[(trow * 4 + 0) * FIN];
    const float* x1p = &xs[(trow * 4 + 1) * FIN];
    const float* x2p = &xs[(trow * 4 + 2) * FIN];
    const float* x3p = &xs[(trow * 4 + 3) * FIN];
#pragma unroll 8
    for (int k = 0; k < FIN; ++k) {
        float4 w4 = *(const float4*)(wp + k * H_DIM);
        float x0 = x0p[k], x1 = x1p[k], x2 = x2p[k], x3 = x3p[k];
        acc[0][0] += x0 * w4.x; acc[0][1] += x0 * w4.y; acc[0][2] += x0 * w4.z; acc[0][3] += x0 * w4.w;
        acc[1][0] += x1 * w4.x; acc[1][1] += x1 * w4.y; acc[1][2] += x1 * w4.z; acc[1][3] += x1 * w4.w;
        acc[2][0] += x2 * w4.x; acc[2][1] += x2 * w4.y; acc[2][2] += x2 * w4.z; acc[2][3] += x2 * w4.w;
        acc[3][0] += x3 * w4.x; acc[3][1] += x3 * w4.y; acc[3][2] += x3 * w4.z; acc[3][3] += x3 * w4.w;
    }
    float4 b4 = *(const float4*)&bias[tcol * 4];
    float4 vs4, vd4;
    if (DO_HSHD) {
        vs4 = *(const float4*)&vs[tcol * 4];
        vd4 = *(const float4*)&vd[tcol * 4];
    }
#pragma unroll
    for (int r = 0; r < 4; ++r) {
        int row = r0 + trow * 4 + r;
        float4 o;
        o.x = fmaxf(acc[r][0] + b4.x, 0.f);
        o.y = fmaxf(acc[r][1] + b4.y, 0.f);
        o.z = fmaxf(acc[r][2] + b4.z, 0.f);
        o.w = fmaxf(acc[r][3] + b4.w, 0.f);
        if (row < n) *(float4*)&Hout[(size_t)row * H_DIM + tcol * 4] = o;
        if (DO_HSHD) {
            float ss = o.x * vs4.x + o.y * vs4.y + o.z * vs4.z + o.w * vs4.w;
            float sd = o.x * vd4.x + o.y * vd4.y + o.z * vd4.z + o.w * vd4.w;
            for (int off = 16; off; off >>= 1) {
                ss += __shfl_xor(ss, off);
                sd += __shfl_xor(sd, off);
            }
            if (tcol == 0 && row < n) { hs[row] = ss; hd[row] = sd; }
        }
    }
}

// ---------------------------------------------------------------------------
// K9: column sums of h (for mean pooling)
__global__ void pool_kernel(const float* __restrict__ hmat, float* __restrict__ pooled,
                            int n) {
    __shared__ float red[256];
    int col = threadIdx.x & 127;
    int half = threadIdx.x >> 7;
    int rows_per_block = (n + gridDim.x - 1) / gridDim.x;
    int r0 = blockIdx.x * rows_per_block;
    int r1 = min(r0 + rows_per_block, n);
    float s = 0.f;
    for (int r = r0 + half; r < r1; r += 2) s += hmat[(size_t)r * H_DIM + col];
    red[threadIdx.x] = s;
    __syncthreads();
    if (half == 0) atomicAdd(&pooled[col], red[threadIdx.x] + red[threadIdx.x + 128]);
}

// ---------------------------------------------------------------------------
// K10: out = tanh(mean(h) @ Wfc + bfc)
__global__ void final_kernel(const float* __restrict__ pooled, const float* __restrict__ Wfc,
                             const float* __restrict__ bfc, float* __restrict__ out, int n) {
    int t = threadIdx.x;
    if (t >= 16) return;
    float inv_n = 1.0f / (float)n;
    float s = 0.f;
    for (int j = 0; j < 128; ++j) s += pooled[j] * inv_n * Wfc[j * 16 + t];
    out[t] = tanhf(s + bfc[t]);
}

// ---------------------------------------------------------------------------
extern "C" void kernel_launch(void* const* d_in, const int* in_sizes, int n_in,
                              void* d_out, int out_size, void* d_ws, size_t ws_size,
                              hipStream_t stream) {
    const float* x   = (const float*)d_in[0];
    const int*   ei  = (const int*)d_in[1];
    const float* ea  = (const float*)d_in[2];
    const float* W1  = (const float*)d_in[3];
    const float* We1 = (const float*)d_in[4];
    const float* as1 = (const float*)d_in[5];
    const float* ad1 = (const float*)d_in[6];
    const float* ae1 = (const float*)d_in[7];
    const float* b1  = (const float*)d_in[8];
    const float* W2  = (const float*)d_in[9];
    const float* We2 = (const float*)d_in[10];
    const float* as2 = (const float*)d_in[11];
    const float* ad2 = (const float*)d_in[12];
    const float* ae2 = (const float*)d_in[13];
    const float* b2  = (const float*)d_in[14];
    const float* Wfc = (const float*)d_in[15];
    const float* bfc = (const float*)d_in[16];
    float* out = (float*)d_out;

    const int n = in_sizes[0] / 64;      // 50000
    const int E = in_sizes[1] / 2;       // 1600000
    const int B = (n + BWID - 1) / BWID; // 391 buckets

    // workspace layout (float units, 256B-aligned blocks)
    size_t o = 0;
    auto alloc = [&](size_t count) { size_t r = o; o += (count + 63) & ~(size_t)63; return r; };
    size_t o_gcnt   = alloc(BMAX);               // int
    size_t o_bstart = alloc(BMAX + 1);           // int
    size_t o_gcur   = alloc(BMAX);               // int
    size_t o_rowptr = alloc(n + 1);              // int
    size_t o_csr    = alloc(4 * (size_t)E);      // int4 per edge
    size_t o_hs     = alloc(n);
    size_t o_hd     = alloc(n);
    size_t o_bufA   = alloc((size_t)n * H_DIM);  // binned (early) / out1, out2 (late)
    size_t o_bufB   = alloc((size_t)n * H_DIM);  // t1 (64-dim) then t2 (128-dim)
    size_t o_c      = alloc(4);
    size_t o_vs1    = alloc(64);
    size_t o_vd1    = alloc(64);
    size_t o_vs2    = alloc(128);
    size_t o_vd2    = alloc(128);
    size_t o_pool   = alloc(128);
    (void)ws_size;  // ~78 MB needed
    // binned (E x int4 = 25.6MB) overlays bufA (25.6MB): binned dies at build,
    // bufA first written by gemm1 afterwards.
    int4* binned = (int4*)((float*)d_ws + o_bufA);

    float* wsf = (float*)d_ws;
    hipMemsetAsync(wsf + o_gcnt, 0, BMAX * sizeof(int), stream);
    hipMemsetAsync(wsf + o_pool, 0, 128 * sizeof(float), stream);

    prep_kernel<<<1, 256, 0, stream>>>(We1, ae1, We2, ae2, W1, as1, ad1, W2, as2, ad2,
        wsf + o_c, wsf + o_vs1, wsf + o_vd1, wsf + o_vs2, wsf + o_vd2);

    int ebg = (E + CHUNK - 1) / CHUNK;  // edge-chunk grid
    count_kernel<<<ebg, 256, 0, stream>>>(ei, (int*)(wsf + o_gcnt), E, B);
    bscan_kernel<<<1, BMAX, 0, stream>>>((int*)(wsf + o_gcnt), (int*)(wsf + o_bstart),
        (int*)(wsf + o_gcur), (int*)(wsf + o_rowptr), B, n, E);
    bin_kernel<<<ebg, 256, 0, stream>>>(ei, ea, wsf + o_c, (int*)(wsf + o_gcur),
        binned, E, B);
    build_kernel<<<B, 256, 0, stream>>>((int*)(wsf + o_bstart), binned,
        (int*)(wsf + o_rowptr), (int4*)(wsf + o_csr), n);

    int wgrid = (n + 3) / 4;  // 4 waves (nodes) per 256-thread block

    // ---- layer 1 (aggregate x, then GEMM) ----
    hshd64_kernel<<<wgrid, 256, 0, stream>>>(x, wsf + o_vs1, wsf + o_vd1,
        wsf + o_hs, wsf + o_hd, n);
    agg64_kernel<<<wgrid, 256, 0, stream>>>((int*)(wsf + o_rowptr), (const int4*)(wsf + o_csr),
        wsf + o_hs, wsf + o_hd, x, wsf + o_bufB, n);
    gemm_kernel<64, true><<<(n + 31) / 32, 256, 0, stream>>>(wsf + o_bufB, W1, b1,
        wsf + o_vs2, wsf + o_vd2, wsf + o_bufA, wsf + o_hs, wsf + o_hd, n);

    // ---- layer 2 (aggregate out1, then GEMM) ----
    agg128_kernel<<<wgrid, 256, 0, stream>>>((int*)(wsf + o_rowptr), (const int4*)(wsf + o_csr),
        wsf + o_hs, wsf + o_hd, wsf + o_bufA, wsf + o_bufB, n);
    gemm_kernel<128, false><<<(n + 31) / 32, 256, 0, stream>>>(wsf + o_bufB, W2, b2,
        nullptr, nullptr, wsf + o_bufA, nullptr, nullptr, n);

    // ---- pooling + head ----
    pool_kernel<<<256, 256, 0, stream>>>(wsf + o_bufA, wsf + o_pool, n);
    final_kernel<<<1, 64, 0, stream>>>(wsf + o_pool, Wfc, bfc, out, n);
}